// Round 1
// baseline (1978.211 us; speedup 1.0000x reference)
//
#include <hip/hip_runtime.h>
#include <math.h>

#define N 320
#define C 128
#define A 32
#define H 4
#define NPOS (N*N)
#define PA 16   // positions per block, kernel A
#define PC 16   // positions per block, kernel C
#define JB 4    // j's per iteration, kernel B

// ---------------- Kernel A: LayerNorm + Q,K,V,G,B projections ----------------
// grid: NPOS/PA blocks, 128 threads
__global__ __launch_bounds__(128)
void ln_proj_kernel(const float* __restrict__ x2d,
                    const float* __restrict__ norm_w,
                    const float* __restrict__ norm_b,
                    const float* __restrict__ Wq,
                    const float* __restrict__ Wk,
                    const float* __restrict__ Wv,
                    const float* __restrict__ Wb,
                    const float* __restrict__ Wg,
                    const float* __restrict__ bg,
                    float* __restrict__ Q,
                    float* __restrict__ K,
                    float* __restrict__ V,
                    float* __restrict__ G,
                    float* __restrict__ Bt) {
    __shared__ float xn[PA][C + 1];
    __shared__ float red[4];
    const int t = threadIdx.x;
    const int lane = t & 63;
    const int wid = t >> 6;
    const int pos0 = blockIdx.x * PA;

    for (int p = 0; p < PA; p++) {
        float x = x2d[(size_t)(pos0 + p) * C + t];
        float s = x, s2 = x * x;
        for (int off = 32; off; off >>= 1) {
            s += __shfl_xor(s, off);
            s2 += __shfl_xor(s2, off);
        }
        if (lane == 0) { red[wid] = s; red[2 + wid] = s2; }
        __syncthreads();
        float mean = (red[0] + red[1]) * (1.0f / C);
        float ms   = (red[2] + red[3]) * (1.0f / C);
        float rstd = rsqrtf(ms - mean * mean + 1e-5f);
        xn[p][t] = (x - mean) * rstd * norm_w[t] + norm_b[t];
        __syncthreads();
    }

    float aq[PA], ak[PA], av[PA], ag[PA];
    for (int p = 0; p < PA; p++) { aq[p] = 0.f; ak[p] = 0.f; av[p] = 0.f; ag[p] = 0.f; }
    for (int c = 0; c < C; c++) {
        float wq = Wq[c * C + t];
        float wk = Wk[c * C + t];
        float wv = Wv[c * C + t];
        float wg = Wg[c * C + t];
        #pragma unroll
        for (int p = 0; p < PA; p++) {
            float xv = xn[p][c];
            aq[p] = fmaf(xv, wq, aq[p]);
            ak[p] = fmaf(xv, wk, ak[p]);
            av[p] = fmaf(xv, wv, av[p]);
            ag[p] = fmaf(xv, wg, ag[p]);
        }
    }
    float bgt = bg[t];
    for (int p = 0; p < PA; p++) {
        size_t base = (size_t)(pos0 + p) * C + t;
        Q[base] = aq[p];
        K[base] = ak[p];
        V[base] = av[p];
        float z = ag[p] + bgt;
        G[base] = 1.0f / (1.0f + __expf(-z));
    }
    // bias projection (4 outputs per position), written transposed: Bt[h][q][p]
    if (t < PA * H) {
        int p = t >> 2, h = t & 3;
        float ab = 0.f;
        for (int c = 0; c < C; c++) ab = fmaf(xn[p][c], Wb[c * H + h], ab);
        int pos = pos0 + p;
        int pi = pos / N;   // first N index (k in attention)
        int qj = pos % N;   // second N index (j in attention)
        Bt[((size_t)h * N + qj) * N + pi] = ab;
    }
}

// ---------------- Kernel B: attention per (i,h) ----------------
// grid: N*H blocks, 320 threads. dynamic LDS ~93 KB.
__global__ __launch_bounds__(320)
void attn_kernel(const float* __restrict__ Q,
                 const float* __restrict__ Km,
                 const float* __restrict__ Vm,
                 const float* __restrict__ G,
                 const float* __restrict__ Bt,
                 const float* __restrict__ mask,
                 float* __restrict__ O) {
    extern __shared__ float lds[];
    float* K_lds = lds;                    // [320][33]  (padded: kills bank conflict)
    float* V_lds = K_lds + 320 * 33;       // [320][32]
    float* w_lds = V_lds + 320 * 32;       // [JB][320]
    float* q_sh  = w_lds + JB * 320;       // [JB][32]
    float* m_lds = q_sh + JB * 32;         // [320]
    float* pv    = m_lds + 320;            // [JB][10][32]
    float* redm  = pv + JB * 10 * 32;      // [JB][8]
    float* reds  = redm + JB * 8;          // [JB][8]

    const int i = blockIdx.x >> 2;
    const int h = blockIdx.x & 3;
    const int t = threadIdx.x;
    const int lane = t & 63;
    const int wid = t >> 6;

    for (int idx = t; idx < N * A; idx += 320) {
        int k = idx >> 5, a = idx & 31;
        size_t g = ((size_t)(i * N + k)) * C + a * H + h;
        K_lds[k * 33 + a] = Km[g];
        V_lds[k * 32 + a] = Vm[g];
    }
    m_lds[t] = mask[i * N + t];
    __syncthreads();

    const float isq = 0.17677669529663687f; // 1/sqrt(32)
    for (int j0 = 0; j0 < N; j0 += JB) {
        if (t < JB * A) {
            int jj = t >> 5, a = t & 31;
            q_sh[jj * 32 + a] = Q[((size_t)(i * N + j0 + jj)) * C + a * H + h];
        }
        __syncthreads();   // sync1: q ready

        float sc[JB];
        {
            float a0 = 0.f, a1 = 0.f, a2 = 0.f, a3 = 0.f;
            const float* kr = &K_lds[t * 33];
            #pragma unroll
            for (int a = 0; a < A; a++) {
                float kv = kr[a];
                a0 = fmaf(q_sh[0 * 32 + a], kv, a0);
                a1 = fmaf(q_sh[1 * 32 + a], kv, a1);
                a2 = fmaf(q_sh[2 * 32 + a], kv, a2);
                a3 = fmaf(q_sh[3 * 32 + a], kv, a3);
            }
            float mk = m_lds[t];
            sc[0] = (fmaf(a0, isq, Bt[((size_t)h * N + j0 + 0) * N + t]) + 100.0f) * mk - 100.0f;
            sc[1] = (fmaf(a1, isq, Bt[((size_t)h * N + j0 + 1) * N + t]) + 100.0f) * mk - 100.0f;
            sc[2] = (fmaf(a2, isq, Bt[((size_t)h * N + j0 + 2) * N + t]) + 100.0f) * mk - 100.0f;
            sc[3] = (fmaf(a3, isq, Bt[((size_t)h * N + j0 + 3) * N + t]) + 100.0f) * mk - 100.0f;
        }

        // block max per jj (320 threads = 5 waves)
        float mx[JB];
        #pragma unroll
        for (int jj = 0; jj < JB; jj++) mx[jj] = sc[jj];
        for (int off = 32; off; off >>= 1) {
            #pragma unroll
            for (int jj = 0; jj < JB; jj++) mx[jj] = fmaxf(mx[jj], __shfl_xor(mx[jj], off));
        }
        if (lane == 0) {
            #pragma unroll
            for (int jj = 0; jj < JB; jj++) redm[jj * 8 + wid] = mx[jj];
        }
        __syncthreads();   // sync2: maxes ready

        float sm[JB];
        #pragma unroll
        for (int jj = 0; jj < JB; jj++) {
            float M = redm[jj * 8 + 0];
            M = fmaxf(M, redm[jj * 8 + 1]);
            M = fmaxf(M, redm[jj * 8 + 2]);
            M = fmaxf(M, redm[jj * 8 + 3]);
            M = fmaxf(M, redm[jj * 8 + 4]);
            float e = __expf(sc[jj] - M);
            w_lds[jj * 320 + t] = e;
            sm[jj] = e;
        }
        for (int off = 32; off; off >>= 1) {
            #pragma unroll
            for (int jj = 0; jj < JB; jj++) sm[jj] += __shfl_xor(sm[jj], off);
        }
        if (lane == 0) {
            #pragma unroll
            for (int jj = 0; jj < JB; jj++) reds[jj * 8 + wid] = sm[jj];
        }
        __syncthreads();   // sync3: sums + w_lds ready

        float inv[JB];
        #pragma unroll
        for (int jj = 0; jj < JB; jj++) {
            float s5 = reds[jj * 8 + 0] + reds[jj * 8 + 1] + reds[jj * 8 + 2]
                     + reds[jj * 8 + 3] + reds[jj * 8 + 4];
            inv[jj] = 1.0f / s5;
        }

        // PV: thread t -> a = t&31, k-segment seg = t>>5 (10 segments of 32)
        {
            int a = t & 31, seg = t >> 5;
            float p0 = 0.f, p1 = 0.f, p2 = 0.f, p3 = 0.f;
            int k0 = seg * 32;
            #pragma unroll
            for (int kk = k0; kk < k0 + 32; kk++) {
                float vv = V_lds[kk * 32 + a];
                p0 = fmaf(w_lds[0 * 320 + kk], vv, p0);
                p1 = fmaf(w_lds[1 * 320 + kk], vv, p1);
                p2 = fmaf(w_lds[2 * 320 + kk], vv, p2);
                p3 = fmaf(w_lds[3 * 320 + kk], vv, p3);
            }
            pv[(0 * 10 + seg) * 32 + a] = p0;
            pv[(1 * 10 + seg) * 32 + a] = p1;
            pv[(2 * 10 + seg) * 32 + a] = p2;
            pv[(3 * 10 + seg) * 32 + a] = p3;
        }
        __syncthreads();   // sync4: partials ready

        if (t < JB * A) {
            int jj = t >> 5, a = t & 31;
            float o = 0.f;
            #pragma unroll
            for (int seg = 0; seg < 10; seg++) o += pv[(jj * 10 + seg) * 32 + a];
            o *= inv[jj];
            size_t g = ((size_t)(i * N + j0 + jj)) * C + a * H + h;
            O[g] = o * G[g];
        }
        // no trailing barrier needed: next-iter writes are ordered by sync1..sync3
    }
}

// ---------------- Kernel C: output projection ----------------
// grid: NPOS/PC blocks, 128 threads
__global__ __launch_bounds__(128)
void outproj_kernel(const float* __restrict__ O,
                    const float* __restrict__ Wo,
                    const float* __restrict__ bo,
                    const float* __restrict__ mask,
                    float* __restrict__ out) {
    __shared__ float osh[PC][C + 1];
    const int t = threadIdx.x;
    const int pos0 = blockIdx.x * PC;
    for (int p = 0; p < PC; p++) osh[p][t] = O[(size_t)(pos0 + p) * C + t];
    __syncthreads();
    float acc[PC];
    float b = bo[t];
    for (int p = 0; p < PC; p++) acc[p] = b;
    for (int c = 0; c < C; c++) {
        float w = Wo[c * C + t];
        #pragma unroll
        for (int p = 0; p < PC; p++) acc[p] = fmaf(osh[p][c], w, acc[p]);
    }
    for (int p = 0; p < PC; p++)
        out[(size_t)(pos0 + p) * C + t] = acc[p] * mask[pos0 + p];
}

// ---------------- launch ----------------
extern "C" void kernel_launch(void* const* d_in, const int* in_sizes, int n_in,
                              void* d_out, int out_size, void* d_ws, size_t ws_size,
                              hipStream_t stream) {
    const float* x2d    = (const float*)d_in[0];
    const float* mask   = (const float*)d_in[1];
    const float* norm_w = (const float*)d_in[2];
    const float* norm_b = (const float*)d_in[3];
    const float* Wq     = (const float*)d_in[4];
    const float* Wk     = (const float*)d_in[5];
    const float* Wv     = (const float*)d_in[6];
    const float* Wb     = (const float*)d_in[7];
    const float* Wg     = (const float*)d_in[8];
    const float* bg     = (const float*)d_in[9];
    const float* Wo     = (const float*)d_in[10];
    const float* bo     = (const float*)d_in[11];
    float* out = (float*)d_out;

    // workspace layout (floats): Q,K,V,G [NPOS*C] each, Bt [H*N*N]
    // total = 4*13107200 + 409600 = 52,838,400 floats = ~211.4 MB
    float* ws = (float*)d_ws;
    float* Q  = ws;
    float* K  = Q + (size_t)NPOS * C;
    float* V  = K + (size_t)NPOS * C;
    float* G  = V + (size_t)NPOS * C;
    float* Bt = G + (size_t)NPOS * C;
    float* O  = Q;  // alias: each (i,h) attn block reads exactly the Q elements it overwrites

    ln_proj_kernel<<<NPOS / PA, 128, 0, stream>>>(x2d, norm_w, norm_b,
                                                  Wq, Wk, Wv, Wb, Wg, bg,
                                                  Q, K, V, G, Bt);

    size_t lds_bytes = (size_t)(320 * 33 + 320 * 32 + JB * 320 + JB * 32 + 320
                                + JB * 10 * 32 + JB * 8 + JB * 8) * sizeof(float);
    attn_kernel<<<N * H, 320, lds_bytes, stream>>>(Q, K, V, G, Bt, mask, O);

    outproj_kernel<<<NPOS / PC, 128, 0, stream>>>(O, Wo, bo, mask, out);
}

// Round 2
// 823.856 us; speedup vs baseline: 2.4012x; 2.4012x over previous
//
#include <hip/hip_runtime.h>
#include <math.h>

#define N 320
#define C 128
#define A 32
#define H 4
#define NPOS (N*N)
#define PA 16   // positions per block, kernel A
#define PC 16   // positions per block, kernel C
#define TK 64   // k-tile rows, kernel B

// ---------------- Kernel A: LayerNorm + Q,K,V,G,B projections ----------------
// grid: NPOS/PA blocks, 128 threads.
// Outputs:
//   Qt[h][a][pos], Gt[h][a][pos]   (plane = h*32+a, coalesced reads in attn)
//   Kh[h][pos][a], Vh[h][pos][a]   (contiguous 32-float rows for tile staging)
//   Bp[h][pos]                     (pos = k*N + j; bias value computed at (k,j))
__global__ __launch_bounds__(128)
void ln_proj_kernel(const float* __restrict__ x2d,
                    const float* __restrict__ norm_w,
                    const float* __restrict__ norm_b,
                    const float* __restrict__ Wq,
                    const float* __restrict__ Wk,
                    const float* __restrict__ Wv,
                    const float* __restrict__ Wb,
                    const float* __restrict__ Wg,
                    const float* __restrict__ bg,
                    float* __restrict__ Qt,
                    float* __restrict__ Kh,
                    float* __restrict__ Vh,
                    float* __restrict__ Gt,
                    float* __restrict__ Bp) {
    __shared__ float xn[PA][C + 1];
    __shared__ float tr1[PA][C + 1];
    __shared__ float tr2[PA][C + 1];
    __shared__ float red[4];
    const int t = threadIdx.x;
    const int lane = t & 63;
    const int wid = t >> 6;
    const int pos0 = blockIdx.x * PA;

    for (int p = 0; p < PA; p++) {
        float x = x2d[(size_t)(pos0 + p) * C + t];
        float s = x, s2 = x * x;
        for (int off = 32; off; off >>= 1) {
            s += __shfl_xor(s, off);
            s2 += __shfl_xor(s2, off);
        }
        if (lane == 0) { red[wid] = s; red[2 + wid] = s2; }
        __syncthreads();
        float mean = (red[0] + red[1]) * (1.0f / C);
        float ms   = (red[2] + red[3]) * (1.0f / C);
        float rstd = rsqrtf(ms - mean * mean + 1e-5f);
        xn[p][t] = (x - mean) * rstd * norm_w[t] + norm_b[t];
        __syncthreads();
    }

    float aq[PA], ak[PA], av[PA], ag[PA];
    #pragma unroll
    for (int p = 0; p < PA; p++) { aq[p] = 0.f; ak[p] = 0.f; av[p] = 0.f; ag[p] = 0.f; }
    for (int c = 0; c < C; c++) {
        float wq = Wq[c * C + t];
        float wk = Wk[c * C + t];
        float wv = Wv[c * C + t];
        float wg = Wg[c * C + t];
        #pragma unroll
        for (int p = 0; p < PA; p++) {
            float xv = xn[p][c];
            aq[p] = fmaf(xv, wq, aq[p]);
            ak[p] = fmaf(xv, wk, ak[p]);
            av[p] = fmaf(xv, wv, av[p]);
            ag[p] = fmaf(xv, wg, ag[p]);
        }
    }

    // bias projection (needs xn): 64 threads, one (p,h) each
    if (t < PA * H) {
        int p = t >> 2, h = t & 3;
        float ab = 0.f;
        for (int c = 0; c < C; c++) ab = fmaf(xn[p][c], Wb[c * H + h], ab);
        Bp[(size_t)h * NPOS + pos0 + p] = ab;
    }

    // Q, G: direct transposed writes (thread owns channel t -> a=t>>2, h=t&3)
    {
        int a_t = t >> 2, h_t = t & 3;
        float bgt = bg[t];
        size_t plane = (size_t)(h_t * 32 + a_t) * NPOS + pos0;
        #pragma unroll
        for (int p = 0; p < PA; p++) {
            Qt[plane + p] = aq[p];
            float z = ag[p] + bgt;
            Gt[plane + p] = 1.0f / (1.0f + __expf(-z));
        }
    }

    // K, V: transpose via LDS, then coalesced [h][pos][a] writes
    #pragma unroll
    for (int p = 0; p < PA; p++) { tr1[p][t] = ak[p]; tr2[p][t] = av[p]; }
    __syncthreads();
    {
        int hI = t >> 5;            // plane 0..3
        int pI = (t & 31) >> 1;     // row 0..15
        int a0 = (t & 1) * 16;      // 0 or 16
        size_t gbase = ((size_t)hI * NPOS + pos0 + pI) * 32 + a0;
        #pragma unroll
        for (int u = 0; u < 4; u++) {
            float4 kv, vv;
            kv.x = tr1[pI][(a0 + u * 4 + 0) * 4 + hI];
            kv.y = tr1[pI][(a0 + u * 4 + 1) * 4 + hI];
            kv.z = tr1[pI][(a0 + u * 4 + 2) * 4 + hI];
            kv.w = tr1[pI][(a0 + u * 4 + 3) * 4 + hI];
            vv.x = tr2[pI][(a0 + u * 4 + 0) * 4 + hI];
            vv.y = tr2[pI][(a0 + u * 4 + 1) * 4 + hI];
            vv.z = tr2[pI][(a0 + u * 4 + 2) * 4 + hI];
            vv.w = tr2[pI][(a0 + u * 4 + 3) * 4 + hI];
            ((float4*)&Kh[gbase])[u] = kv;
            ((float4*)&Vh[gbase])[u] = vv;
        }
    }
}

// ---------------- Kernel B: attention, one j per thread ----------------
// grid: N*H blocks (i,h), 320 threads (thread = j). Online softmax per thread,
// K/V staged in 64-row tiles, broadcast float4 reads, defer-max rescale.
__global__ __launch_bounds__(320)
void attn_kernel(const float* __restrict__ Qt,
                 const float* __restrict__ Kh,
                 const float* __restrict__ Vh,
                 const float* __restrict__ Gt,
                 const float* __restrict__ Bp,
                 const float* __restrict__ mask,
                 float* __restrict__ Ot) {
    __shared__ float Kt[TK * 32];
    __shared__ float Vt[TK * 32];
    __shared__ float m_lds[N];

    const int i = blockIdx.x >> 2;
    const int h = blockIdx.x & 3;
    const int t = threadIdx.x;        // j
    const size_t pos = (size_t)i * N + t;
    const float isq = 0.17677669529663687f; // 1/sqrt(32)

    float q[32], out[32];
    #pragma unroll
    for (int a = 0; a < 32; a++) {
        q[a] = Qt[((size_t)(h * 32 + a)) * NPOS + pos] * isq;
        out[a] = 0.f;
    }
    m_lds[t] = mask[(size_t)i * N + t];

    float m = 0.f, l = 0.f;
    const float* Ksrc = &Kh[((size_t)h * NPOS + (size_t)i * N) * 32];
    const float* Vsrc = &Vh[((size_t)h * NPOS + (size_t)i * N) * 32];
    const float* Bph  = &Bp[(size_t)h * NPOS];

    for (int k0 = 0; k0 < N; k0 += TK) {
        __syncthreads();
        for (int w = t; w < TK * 32; w += 320) {
            Kt[w] = Ksrc[(size_t)k0 * 32 + w];
            Vt[w] = Vsrc[(size_t)k0 * 32 + w];
        }
        __syncthreads();

        for (int kk = 0; kk < TK; kk++) {
            int k = k0 + kk;
            float bias = Bph[(size_t)k * N + t];
            float mk = m_lds[k];
            const float4* kr = (const float4*)&Kt[kk * 32];
            float d0 = 0.f, d1 = 0.f, d2 = 0.f, d3 = 0.f;
            #pragma unroll
            for (int u = 0; u < 8; u++) {
                float4 kv = kr[u];
                d0 = fmaf(q[4 * u + 0], kv.x, d0);
                d1 = fmaf(q[4 * u + 1], kv.y, d1);
                d2 = fmaf(q[4 * u + 2], kv.z, d2);
                d3 = fmaf(q[4 * u + 3], kv.w, d3);
            }
            float dot = (d0 + d1) + (d2 + d3);
            float s = fmaf(dot + bias + 100.0f, mk, -100.0f);
            if (s > m + 8.0f) {           // defer-max: essentially never taken
                float r = __expf(m - s);
                l *= r;
                #pragma unroll
                for (int a = 0; a < 32; a++) out[a] *= r;
                m = s;
            }
            float e = __expf(s - m);
            l += e;
            const float4* vr = (const float4*)&Vt[kk * 32];
            #pragma unroll
            for (int u = 0; u < 8; u++) {
                float4 vv = vr[u];
                out[4 * u + 0] = fmaf(e, vv.x, out[4 * u + 0]);
                out[4 * u + 1] = fmaf(e, vv.y, out[4 * u + 1]);
                out[4 * u + 2] = fmaf(e, vv.z, out[4 * u + 2]);
                out[4 * u + 3] = fmaf(e, vv.w, out[4 * u + 3]);
            }
        }
    }

    float invl = 1.0f / l;
    float* orow = &Ot[((size_t)h * NPOS + pos) * 32];
    #pragma unroll
    for (int u = 0; u < 8; u++) {
        float4 ov;
        ov.x = out[4 * u + 0] * invl * Gt[((size_t)(h * 32 + 4 * u + 0)) * NPOS + pos];
        ov.y = out[4 * u + 1] * invl * Gt[((size_t)(h * 32 + 4 * u + 1)) * NPOS + pos];
        ov.z = out[4 * u + 2] * invl * Gt[((size_t)(h * 32 + 4 * u + 2)) * NPOS + pos];
        ov.w = out[4 * u + 3] * invl * Gt[((size_t)(h * 32 + 4 * u + 3)) * NPOS + pos];
        ((float4*)orow)[u] = ov;
    }
}

// ---------------- Kernel C: output projection ----------------
// grid: NPOS/PC blocks, 128 threads. Reads Ot[h][pos][a].
__global__ __launch_bounds__(128)
void outproj_kernel(const float* __restrict__ Ot,
                    const float* __restrict__ Wo,
                    const float* __restrict__ bo,
                    const float* __restrict__ mask,
                    float* __restrict__ out) {
    __shared__ float osh[PC][C + 1];
    const int t = threadIdx.x;
    const int pos0 = blockIdx.x * PC;
    {
        int a = t >> 2, h = t & 3;
        for (int p = 0; p < PC; p++)
            osh[p][t] = Ot[((size_t)h * NPOS + pos0 + p) * 32 + a];
    }
    __syncthreads();
    float acc[PC];
    float b = bo[t];
    #pragma unroll
    for (int p = 0; p < PC; p++) acc[p] = b;
    for (int c = 0; c < C; c++) {
        float w = Wo[c * C + t];
        #pragma unroll
        for (int p = 0; p < PC; p++) acc[p] = fmaf(osh[p][c], w, acc[p]);
    }
    #pragma unroll
    for (int p = 0; p < PC; p++)
        out[(size_t)(pos0 + p) * C + t] = acc[p] * mask[pos0 + p];
}

// ---------------- launch ----------------
extern "C" void kernel_launch(void* const* d_in, const int* in_sizes, int n_in,
                              void* d_out, int out_size, void* d_ws, size_t ws_size,
                              hipStream_t stream) {
    const float* x2d    = (const float*)d_in[0];
    const float* mask   = (const float*)d_in[1];
    const float* norm_w = (const float*)d_in[2];
    const float* norm_b = (const float*)d_in[3];
    const float* Wq     = (const float*)d_in[4];
    const float* Wk     = (const float*)d_in[5];
    const float* Wv     = (const float*)d_in[6];
    const float* Wb     = (const float*)d_in[7];
    const float* Wg     = (const float*)d_in[8];
    const float* bg     = (const float*)d_in[9];
    const float* Wo     = (const float*)d_in[10];
    const float* bo     = (const float*)d_in[11];
    float* out = (float*)d_out;

    // ws floats: Qt, Kh, Vh, Gt [NPOS*C each], Bp [H*NPOS]  -> ~211.4 MB
    float* ws = (float*)d_ws;
    float* Qt = ws;
    float* Kh = Qt + (size_t)NPOS * C;
    float* Vh = Kh + (size_t)NPOS * C;
    float* Gt = Vh + (size_t)NPOS * C;
    float* Bp = Gt + (size_t)NPOS * C;
    float* Ot = Vh;  // alias: block (i,h) writes exactly the Vh addresses it read

    ln_proj_kernel<<<NPOS / PA, 128, 0, stream>>>(x2d, norm_w, norm_b,
                                                  Wq, Wk, Wv, Wb, Wg, bg,
                                                  Qt, Kh, Vh, Gt, Bp);

    attn_kernel<<<N * H, 320, 0, stream>>>(Qt, Kh, Vh, Gt, Bp, mask, Ot);

    outproj_kernel<<<NPOS / PC, 128, 0, stream>>>(Ot, Wo, bo, mask, out);
}

// Round 3
// 475.710 us; speedup vs baseline: 4.1584x; 1.7318x over previous
//
#include <hip/hip_runtime.h>
#include <hip/hip_bf16.h>
#include <math.h>

#define N 320
#define C 128
#define A 32
#define H 4
#define NPOS (N*N)
#define PA 16   // positions per block, kernel A
#define PC 16   // positions per block, kernel C

typedef __attribute__((ext_vector_type(8))) __bf16 bf16x8;
typedef __attribute__((ext_vector_type(16))) float f32x16;

union frag_u { int4 i; bf16x8 v; unsigned u[4]; };

#define MFMA32(va, vb, vc) __builtin_amdgcn_mfma_f32_32x32x16_bf16((va), (vb), (vc), 0, 0, 0)

static __device__ __forceinline__ unsigned pk_bf16(float lo, float hi) {
    union { __hip_bfloat162 h; unsigned u; } cv;
    cv.h = __float22bfloat162_rn(make_float2(lo, hi));
    return cv.u;
}

// ---------------- Kernel A: LayerNorm + Q,K,V,G,B projections ----------------
// Outputs:
//   Qb[h][pos][a] bf16 rows (q * isq pre-scaled), Kb[h][pos][a] bf16 rows
//   Vta[h*32+a][pos] bf16 planes
//   Gt[h*32+a][pos]  f32 planes
//   Bp[h][pos]       f32  (pos=(r1,r2); bias consumed as b[k=r1][j=r2])
__global__ __launch_bounds__(128)
void ln_proj_kernel(const float* __restrict__ x2d,
                    const float* __restrict__ norm_w,
                    const float* __restrict__ norm_b,
                    const float* __restrict__ Wq,
                    const float* __restrict__ Wk,
                    const float* __restrict__ Wv,
                    const float* __restrict__ Wb,
                    const float* __restrict__ Wg,
                    const float* __restrict__ bg,
                    unsigned short* __restrict__ Qb,
                    unsigned short* __restrict__ Kb,
                    unsigned short* __restrict__ Vta,
                    float* __restrict__ Gt,
                    float* __restrict__ Bp) {
    __shared__ float xn[PA][C + 1];
    __shared__ float tr1[PA][C + 1];
    __shared__ float tr2[PA][C + 1];
    __shared__ float red[4];
    const int t = threadIdx.x;
    const int lane = t & 63;
    const int wid = t >> 6;
    const int pos0 = blockIdx.x * PA;
    const float isq = 0.17677669529663687f; // 1/sqrt(32)

    for (int p = 0; p < PA; p++) {
        float x = x2d[(size_t)(pos0 + p) * C + t];
        float s = x, s2 = x * x;
        for (int off = 32; off; off >>= 1) {
            s += __shfl_xor(s, off);
            s2 += __shfl_xor(s2, off);
        }
        if (lane == 0) { red[wid] = s; red[2 + wid] = s2; }
        __syncthreads();
        float mean = (red[0] + red[1]) * (1.0f / C);
        float ms   = (red[2] + red[3]) * (1.0f / C);
        float rstd = rsqrtf(ms - mean * mean + 1e-5f);
        xn[p][t] = (x - mean) * rstd * norm_w[t] + norm_b[t];
        __syncthreads();
    }

    float aq[PA], ak[PA], av[PA], ag[PA];
    #pragma unroll
    for (int p = 0; p < PA; p++) { aq[p] = 0.f; ak[p] = 0.f; av[p] = 0.f; ag[p] = 0.f; }
    for (int c = 0; c < C; c++) {
        float wq = Wq[c * C + t];
        float wk = Wk[c * C + t];
        float wv = Wv[c * C + t];
        float wg = Wg[c * C + t];
        #pragma unroll
        for (int p = 0; p < PA; p++) {
            float xv = xn[p][c];
            aq[p] = fmaf(xv, wq, aq[p]);
            ak[p] = fmaf(xv, wk, ak[p]);
            av[p] = fmaf(xv, wv, av[p]);
            ag[p] = fmaf(xv, wg, ag[p]);
        }
    }

    // bias projection (needs xn)
    if (t < PA * H) {
        int p = t >> 2, hh = t & 3;
        float ab = 0.f;
        for (int c = 0; c < C; c++) ab = fmaf(xn[p][c], Wb[c * H + hh], ab);
        Bp[(size_t)hh * NPOS + pos0 + p] = ab;
    }

    // V (bf16 planes) + G (f32 planes): thread owns channel t -> a=t>>2, h=t&3
    {
        int a_t = t >> 2, h_t = t & 3;
        float bgt = bg[t];
        size_t off = (size_t)(h_t * 32 + a_t) * NPOS + pos0;
        unsigned* vdst = ((unsigned*)Vta) + (off >> 1);
        #pragma unroll
        for (int p = 0; p < PA; p += 2)
            vdst[p >> 1] = pk_bf16(av[p], av[p + 1]);
        #pragma unroll
        for (int p = 0; p < PA; p++) {
            float z = ag[p] + bgt;
            Gt[off + p] = 1.0f / (1.0f + __expf(-z));
        }
    }

    // Q,K: transpose via LDS, write bf16 rows [h][pos][a]
    #pragma unroll
    for (int p = 0; p < PA; p++) { tr1[p][t] = aq[p] * isq; tr2[p][t] = ak[p]; }
    __syncthreads();
    {
        int hI = t >> 5;
        int pI = (t & 31) >> 1;
        int a0 = (t & 1) * 16;
        size_t row = (size_t)hI * NPOS + pos0 + pI;
        unsigned uq[8], uk[8];
        #pragma unroll
        for (int u = 0; u < 8; u++) {
            uq[u] = pk_bf16(tr1[pI][(a0 + 2*u) * 4 + hI], tr1[pI][(a0 + 2*u + 1) * 4 + hI]);
            uk[u] = pk_bf16(tr2[pI][(a0 + 2*u) * 4 + hI], tr2[pI][(a0 + 2*u + 1) * 4 + hI]);
        }
        int4* qdst = (int4*)((char*)Qb + row * 64 + a0 * 2);
        int4* kdst = (int4*)((char*)Kb + row * 64 + a0 * 2);
        qdst[0] = make_int4(uq[0], uq[1], uq[2], uq[3]);
        qdst[1] = make_int4(uq[4], uq[5], uq[6], uq[7]);
        kdst[0] = make_int4(uk[0], uk[1], uk[2], uk[3]);
        kdst[1] = make_int4(uk[4], uk[5], uk[6], uk[7]);
    }
}

// ---------------- Kernel B: MFMA attention per (i,h) ----------------
// 5 waves x 64 j each; swapped QK^T (C[k][j]) -> lane-local softmax;
// P repacked to PV B-frags via shfl half-swaps; V^T A-frags from swizzled LDS.
__global__ __launch_bounds__(320, 2)
void attn_kernel(const unsigned short* __restrict__ Qb,
                 const unsigned short* __restrict__ Kb,
                 const unsigned short* __restrict__ Vta,
                 const float* __restrict__ Gt,
                 const float* __restrict__ Bp,
                 const float* __restrict__ mask,
                 float* __restrict__ Ot) {
    __shared__ __align__(16) unsigned char Klds[320 * 64];
    __shared__ __align__(16) unsigned char Vlds[32 * 640];
    __shared__ float mlds[N];

    const int i = blockIdx.x >> 2;
    const int h = blockIdx.x & 3;
    const int t = threadIdx.x;
    const int lane = t & 63;
    const int w = t >> 6;
    const int col = lane & 31;
    const int hi = lane >> 5;
    const int jt0 = w * 64;

    // Q fragments from global (row jrow, 8 bf16 granules)
    frag_u qf[2][2];
    const char* qbase = (const char*)Qb + ((size_t)h * NPOS + (size_t)i * N) * 64;
    #pragma unroll
    for (int jt = 0; jt < 2; ++jt) {
        int jrow = jt0 + jt * 32 + col;
        #pragma unroll
        for (int cf = 0; cf < 2; ++cf)
            qf[jt][cf].i = *(const int4*)(qbase + (size_t)jrow * 64 + cf * 32 + hi * 16);
    }

    // stage K rows (swizzled granule slots)
    const char* kbsrc = (const char*)Kb + ((size_t)h * NPOS + (size_t)i * N) * 64;
    #pragma unroll
    for (int it = 0; it < 4; ++it) {
        int tt = t + it * 320;
        int k = tt >> 2, gc = tt & 3;
        int4 val = *(const int4*)(kbsrc + (size_t)k * 64 + gc * 16);
        *(int4*)(Klds + k * 64 + ((gc ^ ((k >> 1) & 3)) << 4)) = val;
    }
    // stage V^T planes (swizzled)
    const char* vbsrc = (const char*)Vta + ((size_t)h * 32 * NPOS + (size_t)i * N) * 2;
    #pragma unroll
    for (int it = 0; it < 4; ++it) {
        int tt = t + it * 320;
        int a = tt / 40, kg = tt % 40;
        int4 val = *(const int4*)(vbsrc + (size_t)a * NPOS * 2 + kg * 16);
        *(int4*)(Vlds + a * 640 + ((kg ^ (a & 7)) << 4)) = val;
    }
    mlds[t] = mask[(size_t)i * N + t];
    __syncthreads();

    f32x16 accO[2];
    #pragma unroll
    for (int r = 0; r < 16; ++r) { accO[0][r] = 0.f; accO[1][r] = 0.f; }
    float mrun[2] = { -3e38f, -3e38f };
    float lsum[2] = { 0.f, 0.f };
    const float* bpj = Bp + (size_t)h * NPOS;

    for (int kt = 0; kt < 10; ++kt) {
        const int kbase = kt * 32;
        const int krow = kbase + col;
        frag_u kf0, kf1, vf0, vf1;
        kf0.i = *(const int4*)(Klds + krow * 64 + (((0 + hi) ^ ((krow >> 1) & 3)) << 4));
        kf1.i = *(const int4*)(Klds + krow * 64 + (((2 + hi) ^ ((krow >> 1) & 3)) << 4));
        vf0.i = *(const int4*)(Vlds + col * 640 + (((kt * 4 + 0 + hi) ^ (col & 7)) << 4));
        vf1.i = *(const int4*)(Vlds + col * 640 + (((kt * 4 + 2 + hi) ^ (col & 7)) << 4));

        float mk[16];
        #pragma unroll
        for (int r = 0; r < 16; ++r) {
            const int patr = (r & 3) + 8 * (r >> 2);
            mk[r] = mlds[kbase + patr + 4 * hi];
        }

        #pragma unroll
        for (int jt = 0; jt < 2; ++jt) {
            const int jcol = jt0 + jt * 32 + col;
            f32x16 S;
            #pragma unroll
            for (int r = 0; r < 16; ++r) S[r] = 0.f;
            S = MFMA32(kf0.v, qf[jt][0].v, S);
            S = MFMA32(kf1.v, qf[jt][1].v, S);

            float sv[16];
            #pragma unroll
            for (int r = 0; r < 16; ++r) {
                const int patr = (r & 3) + 8 * (r >> 2);
                const int kk = kbase + patr + 4 * hi;
                float b = bpj[kk * N + jcol];
                sv[r] = fmaf(S[r] + b, mk[r], fmaf(100.f, mk[r], -100.f));
            }

            float mt = sv[0];
            #pragma unroll
            for (int r = 1; r < 16; ++r) mt = fmaxf(mt, sv[r]);
            mt = fmaxf(mt, __shfl_xor(mt, 32));

            if (__any(mt > mrun[jt] + 8.0f)) {
                float mnew = fmaxf(mrun[jt], mt);
                float rs = __expf(mrun[jt] - mnew);
                lsum[jt] *= rs;
                #pragma unroll
                for (int r = 0; r < 16; ++r) accO[jt][r] *= rs;
                mrun[jt] = mnew;
            }

            float pe[16];
            float ls = 0.f;
            #pragma unroll
            for (int r = 0; r < 16; ++r) {
                pe[r] = __expf(sv[r] - mrun[jt]);
                ls += pe[r];
            }
            lsum[jt] += ls;

            unsigned p[8];
            #pragma unroll
            for (int q = 0; q < 8; ++q) p[q] = pk_bf16(pe[2 * q], pe[2 * q + 1]);
            unsigned sp[8];
            #pragma unroll
            for (int q = 0; q < 8; ++q) sp[q] = (unsigned)__shfl_xor((int)p[q], 32);

            frag_u bf0, bf1;
            bf0.u[0] = hi ? sp[2] : p[0];
            bf0.u[1] = hi ? sp[3] : p[1];
            bf0.u[2] = hi ? p[2]  : sp[0];
            bf0.u[3] = hi ? p[3]  : sp[1];
            bf1.u[0] = hi ? sp[6] : p[4];
            bf1.u[1] = hi ? sp[7] : p[5];
            bf1.u[2] = hi ? p[6]  : sp[4];
            bf1.u[3] = hi ? p[7]  : sp[5];

            accO[jt] = MFMA32(vf0.v, bf0.v, accO[jt]);
            accO[jt] = MFMA32(vf1.v, bf1.v, accO[jt]);
        }
    }

    // epilogue: normalize, gate, store f32 planes
    #pragma unroll
    for (int jt = 0; jt < 2; ++jt) {
        float lt = lsum[jt] + __shfl_xor(lsum[jt], 32);
        float inv = 1.0f / lt;
        const int jcol = jt0 + jt * 32 + col;
        #pragma unroll
        for (int r = 0; r < 16; ++r) {
            const int a = (r & 3) + 8 * (r >> 2) + 4 * hi;
            size_t off = (size_t)(h * 32 + a) * NPOS + (size_t)i * N + jcol;
            Ot[off] = accO[jt][r] * inv * Gt[off];
        }
    }
}

// ---------------- Kernel C: output projection ----------------
// Reads Ot planes [h*32+a][pos]; channel c = a*4 + h.
__global__ __launch_bounds__(128)
void outproj_kernel(const float* __restrict__ Ot,
                    const float* __restrict__ Wo,
                    const float* __restrict__ bo,
                    const float* __restrict__ mask,
                    float* __restrict__ out) {
    __shared__ float osh[PC][C + 1];
    const int t = threadIdx.x;
    const int pos0 = blockIdx.x * PC;
    {
        int c = ((t & 31) << 2) | (t >> 5);   // plane t -> channel a*4+h
        const float4* src = (const float4*)(Ot + (size_t)t * NPOS + pos0);
        #pragma unroll
        for (int u = 0; u < 4; ++u) {
            float4 vv = src[u];
            osh[4*u+0][c] = vv.x; osh[4*u+1][c] = vv.y;
            osh[4*u+2][c] = vv.z; osh[4*u+3][c] = vv.w;
        }
    }
    __syncthreads();
    float acc[PC];
    float b = bo[t];
    #pragma unroll
    for (int p = 0; p < PC; p++) acc[p] = b;
    for (int c = 0; c < C; c++) {
        float wv = Wo[c * C + t];
        #pragma unroll
        for (int p = 0; p < PC; p++) acc[p] = fmaf(osh[p][c], wv, acc[p]);
    }
    #pragma unroll
    for (int p = 0; p < PC; p++)
        out[(size_t)(pos0 + p) * C + t] = acc[p] * mask[pos0 + p];
}

// ---------------- launch ----------------
extern "C" void kernel_launch(void* const* d_in, const int* in_sizes, int n_in,
                              void* d_out, int out_size, void* d_ws, size_t ws_size,
                              hipStream_t stream) {
    const float* x2d    = (const float*)d_in[0];
    const float* mask   = (const float*)d_in[1];
    const float* norm_w = (const float*)d_in[2];
    const float* norm_b = (const float*)d_in[3];
    const float* Wq     = (const float*)d_in[4];
    const float* Wk     = (const float*)d_in[5];
    const float* Wv     = (const float*)d_in[6];
    const float* Wb     = (const float*)d_in[7];
    const float* Wg     = (const float*)d_in[8];
    const float* bg     = (const float*)d_in[9];
    const float* Wo     = (const float*)d_in[10];
    const float* bo     = (const float*)d_in[11];
    float* out = (float*)d_out;

    // ws: Gt f32[NPOS*C], Bp f32[H*NPOS], Ot f32[NPOS*C], Qb/Kb/Vta bf16[NPOS*C]
    float* Gt = (float*)d_ws;
    float* Bp = Gt + (size_t)NPOS * C;
    float* Ot = Bp + (size_t)H * NPOS;
    unsigned short* Qb  = (unsigned short*)(Ot + (size_t)NPOS * C);
    unsigned short* Kb  = Qb + (size_t)NPOS * C;
    unsigned short* Vta = Kb + (size_t)NPOS * C;

    ln_proj_kernel<<<NPOS / PA, 128, 0, stream>>>(x2d, norm_w, norm_b,
                                                  Wq, Wk, Wv, Wb, Wg, bg,
                                                  Qb, Kb, Vta, Gt, Bp);

    attn_kernel<<<N * H, 320, 0, stream>>>(Qb, Kb, Vta, Gt, Bp, mask, Ot);

    outproj_kernel<<<NPOS / PC, 128, 0, stream>>>(Ot, Wo, bo, mask, out);
}

// Round 4
// 314.860 us; speedup vs baseline: 6.2828x; 1.5109x over previous
//
#include <hip/hip_runtime.h>
#include <hip/hip_bf16.h>
#include <math.h>

#define N 320
#define C 128
#define A 32
#define H 4
#define NPOS (N*N)
#define PC 16   // positions per block, kernel C

typedef __attribute__((ext_vector_type(8))) __bf16 bf16x8;
typedef __attribute__((ext_vector_type(16))) float f32x16;

union frag_u { int4 i; bf16x8 v; unsigned u[4]; };

#define MFMA32(va, vb, vc) __builtin_amdgcn_mfma_f32_32x32x16_bf16((va), (vb), (vc), 0, 0, 0)

static __device__ __forceinline__ unsigned pk_bf16(float lo, float hi) {
    union { __hip_bfloat162 h; unsigned u; } cv;
    cv.h = __float22bfloat162_rn(make_float2(lo, hi));
    return cv.u;
}

// ---------------- Kernel W: weights -> bf16 B-fragment order ----------------
// WF[mat][ct][kk][lane] : 16B per lane; lane l holds W[kk*16+8*(l>>5)+e][ct*32+(l&31)]
// mat 0..3 = Wq(*isq), Wk, Wv, Wg.
__global__ __launch_bounds__(256)
void wprep_kernel(const float* __restrict__ Wq,
                  const float* __restrict__ Wk,
                  const float* __restrict__ Wv,
                  const float* __restrict__ Wg,
                  unsigned short* __restrict__ WF) {
    const float isq = 0.17677669529663687f; // 1/sqrt(32)
    int tid = blockIdx.x * 256 + threadIdx.x;   // 8192 total
    int lane = tid & 63;
    int kk = (tid >> 6) & 7;
    int ct = (tid >> 9) & 3;
    int mat = tid >> 11;
    const float* src = (mat == 0) ? Wq : (mat == 1) ? Wk : (mat == 2) ? Wv : Wg;
    float scl = (mat == 0) ? isq : 1.0f;
    int col = ct * 32 + (lane & 31);
    int c0 = kk * 16 + (lane >> 5) * 8;
    float v[8];
    #pragma unroll
    for (int e = 0; e < 8; e++) v[e] = src[(size_t)(c0 + e) * 128 + col] * scl;
    int4 out;
    out.x = pk_bf16(v[0], v[1]);
    out.y = pk_bf16(v[2], v[3]);
    out.z = pk_bf16(v[4], v[5]);
    out.w = pk_bf16(v[6], v[7]);
    *(int4*)((char*)WF + (size_t)tid * 16) = out;
}

// ---------------- Kernel A: LayerNorm + MFMA projections ----------------
// 1600 blocks x 256 threads; 64 positions per block; wave w computes matrix w.
__global__ __launch_bounds__(256)
void ln_proj_kernel(const float* __restrict__ x2d,
                    const float* __restrict__ norm_w,
                    const float* __restrict__ norm_b,
                    const float* __restrict__ Wb,
                    const float* __restrict__ bg,
                    const unsigned short* __restrict__ WF,
                    unsigned short* __restrict__ Qb,
                    unsigned short* __restrict__ Kb,
                    unsigned short* __restrict__ Vta,
                    float* __restrict__ Gt,
                    float* __restrict__ Bp) {
    __shared__ __align__(16) unsigned char xnb[64 * 256];   // bf16 [64][128], XOR-swizzled granules
    __shared__ float stage[4][32 * 65];                     // per-wave f32 [col][row] stage

    const int t = threadIdx.x;
    const int gpos0 = blockIdx.x * 64;

    // ---- Phase 1: LN + bias projection + bf16 pack to LDS ----
    {
        const int r = t >> 2, s = t & 3;
        const float4* src = (const float4*)(x2d + (size_t)(gpos0 + r) * 128 + s * 32);
        float4 xv[8];
        #pragma unroll
        for (int u = 0; u < 8; u++) xv[u] = src[u];
        float sum = 0.f, sq = 0.f;
        #pragma unroll
        for (int u = 0; u < 8; u++) {
            sum += xv[u].x + xv[u].y + xv[u].z + xv[u].w;
            sq += xv[u].x * xv[u].x + xv[u].y * xv[u].y
                + xv[u].z * xv[u].z + xv[u].w * xv[u].w;
        }
        sum += __shfl_xor(sum, 1); sum += __shfl_xor(sum, 2);
        sq  += __shfl_xor(sq, 1);  sq  += __shfl_xor(sq, 2);
        float mean = sum * (1.0f / 128.0f);
        float var  = sq * (1.0f / 128.0f) - mean * mean;
        float rstd = rsqrtf(var + 1e-5f);

        const float4* wsrc = (const float4*)(norm_w + s * 32);
        const float4* bsrc = (const float4*)(norm_b + s * 32);
        const float4* wb4  = (const float4*)Wb;
        float pb0 = 0.f, pb1 = 0.f, pb2 = 0.f, pb3 = 0.f;
        float4 xe;
        #pragma unroll
        for (int u = 0; u < 8; u++) {
            float4 wv = wsrc[u], bv = bsrc[u], x4 = xv[u];
            float4 xn;
            xn.x = (x4.x - mean) * rstd * wv.x + bv.x;
            xn.y = (x4.y - mean) * rstd * wv.y + bv.y;
            xn.z = (x4.z - mean) * rstd * wv.z + bv.z;
            xn.w = (x4.w - mean) * rstd * wv.w + bv.w;
            int cb = s * 32 + u * 4;
            float4 w0 = wb4[cb + 0], w1 = wb4[cb + 1], w2 = wb4[cb + 2], w3 = wb4[cb + 3];
            pb0 = fmaf(xn.x, w0.x, fmaf(xn.y, w1.x, fmaf(xn.z, w2.x, fmaf(xn.w, w3.x, pb0))));
            pb1 = fmaf(xn.x, w0.y, fmaf(xn.y, w1.y, fmaf(xn.z, w2.y, fmaf(xn.w, w3.y, pb1))));
            pb2 = fmaf(xn.x, w0.z, fmaf(xn.y, w1.z, fmaf(xn.z, w2.z, fmaf(xn.w, w3.z, pb2))));
            pb3 = fmaf(xn.x, w0.w, fmaf(xn.y, w1.w, fmaf(xn.z, w2.w, fmaf(xn.w, w3.w, pb3))));
            if (u & 1) {
                int g = s * 4 + (u >> 1);
                int4 gr;
                gr.x = pk_bf16(xe.x, xe.y);
                gr.y = pk_bf16(xe.z, xe.w);
                gr.z = pk_bf16(xn.x, xn.y);
                gr.w = pk_bf16(xn.z, xn.w);
                *(int4*)(xnb + r * 256 + ((g ^ (r & 7)) << 4)) = gr;
            } else {
                xe = xn;
            }
        }
        pb0 += __shfl_xor(pb0, 1); pb0 += __shfl_xor(pb0, 2);
        pb1 += __shfl_xor(pb1, 1); pb1 += __shfl_xor(pb1, 2);
        pb2 += __shfl_xor(pb2, 1); pb2 += __shfl_xor(pb2, 2);
        pb3 += __shfl_xor(pb3, 1); pb3 += __shfl_xor(pb3, 2);
        float pbsel = (s == 0) ? pb0 : (s == 1) ? pb1 : (s == 2) ? pb2 : pb3;
        Bp[(size_t)s * NPOS + gpos0 + r] = pbsel;
    }
    __syncthreads();

    // ---- Phase 2+3: per-wave MFMA GEMM + epilogue ----
    const int lane = t & 63;
    const int w = t >> 6;
    const int col = lane & 31;
    const int hi = lane >> 5;

    frag_u af[2][8];
    #pragma unroll
    for (int rt = 0; rt < 2; rt++)
        #pragma unroll
        for (int kk = 0; kk < 8; kk++) {
            int row = rt * 32 + col;
            af[rt][kk].i = *(const int4*)(xnb + row * 256 + (((kk * 2 + hi) ^ (row & 7)) << 4));
        }

    const char* wf = (const char*)WF + (size_t)w * 4 * 8 * 1024;
    float* stage_w = stage[w];

    for (int ct = 0; ct < 4; ct++) {
        f32x16 acc0, acc1;
        #pragma unroll
        for (int r = 0; r < 16; r++) { acc0[r] = 0.f; acc1[r] = 0.f; }
        #pragma unroll
        for (int kk = 0; kk < 8; kk++) {
            frag_u bf;
            bf.i = *(const int4*)(wf + (ct * 8 + kk) * 1024 + lane * 16);
            acc0 = MFMA32(af[0][kk].v, bf.v, acc0);
            acc1 = MFMA32(af[1][kk].v, bf.v, acc1);
        }
        #pragma unroll
        for (int r = 0; r < 16; r++) {
            int patr = (r & 3) + 8 * (r >> 2) + 4 * hi;
            stage_w[col * 65 + patr] = acc0[r];
            stage_w[col * 65 + 32 + patr] = acc1[r];
        }
        __builtin_amdgcn_s_waitcnt(0);  // lgkmcnt(0): stage writes visible wave-wide
        if (w < 2) {
            // Q / K rows: Qb[h][pos][a] bf16
            char* dst = (w == 0) ? (char*)Qb : (char*)Kb;
            #pragma unroll
            for (int h = 0; h < 4; h++) {
                float f[8];
                #pragma unroll
                for (int u = 0; u < 8; u++) f[u] = stage_w[(u * 4 + h) * 65 + lane];
                int4 val;
                val.x = pk_bf16(f[0], f[1]);
                val.y = pk_bf16(f[2], f[3]);
                val.z = pk_bf16(f[4], f[5]);
                val.w = pk_bf16(f[6], f[7]);
                *(int4*)(dst + ((size_t)h * NPOS + gpos0 + lane) * 64 + ct * 16) = val;
            }
        } else if (w == 2) {
            // V planes: Vta[h*32+a][pos] bf16
            int cc = lane & 31, half = lane >> 5;
            int plane = (cc & 3) * 32 + ct * 8 + (cc >> 2);
            unsigned pk[16];
            #pragma unroll
            for (int j2 = 0; j2 < 16; j2++)
                pk[j2] = pk_bf16(stage_w[cc * 65 + half * 32 + 2 * j2],
                                 stage_w[cc * 65 + half * 32 + 2 * j2 + 1]);
            int4* dst = (int4*)((char*)Vta + ((size_t)plane * NPOS + gpos0 + half * 32) * 2);
            dst[0] = make_int4(pk[0], pk[1], pk[2], pk[3]);
            dst[1] = make_int4(pk[4], pk[5], pk[6], pk[7]);
            dst[2] = make_int4(pk[8], pk[9], pk[10], pk[11]);
            dst[3] = make_int4(pk[12], pk[13], pk[14], pk[15]);
        } else {
            // G planes: Gt[h*32+a][pos] f32, sigmoid(acc + bg)
            int cc = lane & 31, half = lane >> 5;
            int plane = (cc & 3) * 32 + ct * 8 + (cc >> 2);
            float bgv = bg[ct * 32 + cc];
            float4* dst = (float4*)(Gt + (size_t)plane * NPOS + gpos0 + half * 32);
            #pragma unroll
            for (int u = 0; u < 8; u++) {
                float4 o;
                float z0 = stage_w[cc * 65 + half * 32 + 4 * u + 0] + bgv;
                float z1 = stage_w[cc * 65 + half * 32 + 4 * u + 1] + bgv;
                float z2 = stage_w[cc * 65 + half * 32 + 4 * u + 2] + bgv;
                float z3 = stage_w[cc * 65 + half * 32 + 4 * u + 3] + bgv;
                o.x = 1.0f / (1.0f + __expf(-z0));
                o.y = 1.0f / (1.0f + __expf(-z1));
                o.z = 1.0f / (1.0f + __expf(-z2));
                o.w = 1.0f / (1.0f + __expf(-z3));
                dst[u] = o;
            }
        }
        __builtin_amdgcn_s_waitcnt(0);  // drain before stage reuse next ct
    }
}

// ---------------- Kernel B: MFMA attention per (i,h) ---------------- (unchanged)
__global__ __launch_bounds__(320, 2)
void attn_kernel(const unsigned short* __restrict__ Qb,
                 const unsigned short* __restrict__ Kb,
                 const unsigned short* __restrict__ Vta,
                 const float* __restrict__ Gt,
                 const float* __restrict__ Bp,
                 const float* __restrict__ mask,
                 float* __restrict__ Ot) {
    __shared__ __align__(16) unsigned char Klds[320 * 64];
    __shared__ __align__(16) unsigned char Vlds[32 * 640];
    __shared__ float mlds[N];

    const int i = blockIdx.x >> 2;
    const int h = blockIdx.x & 3;
    const int t = threadIdx.x;
    const int lane = t & 63;
    const int w = t >> 6;
    const int col = lane & 31;
    const int hi = lane >> 5;
    const int jt0 = w * 64;

    frag_u qf[2][2];
    const char* qbase = (const char*)Qb + ((size_t)h * NPOS + (size_t)i * N) * 64;
    #pragma unroll
    for (int jt = 0; jt < 2; ++jt) {
        int jrow = jt0 + jt * 32 + col;
        #pragma unroll
        for (int cf = 0; cf < 2; ++cf)
            qf[jt][cf].i = *(const int4*)(qbase + (size_t)jrow * 64 + cf * 32 + hi * 16);
    }

    const char* kbsrc = (const char*)Kb + ((size_t)h * NPOS + (size_t)i * N) * 64;
    #pragma unroll
    for (int it = 0; it < 4; ++it) {
        int tt = t + it * 320;
        int k = tt >> 2, gc = tt & 3;
        int4 val = *(const int4*)(kbsrc + (size_t)k * 64 + gc * 16);
        *(int4*)(Klds + k * 64 + ((gc ^ ((k >> 1) & 3)) << 4)) = val;
    }
    const char* vbsrc = (const char*)Vta + ((size_t)h * 32 * NPOS + (size_t)i * N) * 2;
    #pragma unroll
    for (int it = 0; it < 4; ++it) {
        int tt = t + it * 320;
        int a = tt / 40, kg = tt % 40;
        int4 val = *(const int4*)(vbsrc + (size_t)a * NPOS * 2 + kg * 16);
        *(int4*)(Vlds + a * 640 + ((kg ^ (a & 7)) << 4)) = val;
    }
    mlds[t] = mask[(size_t)i * N + t];
    __syncthreads();

    f32x16 accO[2];
    #pragma unroll
    for (int r = 0; r < 16; ++r) { accO[0][r] = 0.f; accO[1][r] = 0.f; }
    float mrun[2] = { -3e38f, -3e38f };
    float lsum[2] = { 0.f, 0.f };
    const float* bpj = Bp + (size_t)h * NPOS;

    for (int kt = 0; kt < 10; ++kt) {
        const int kbase = kt * 32;
        const int krow = kbase + col;
        frag_u kf0, kf1, vf0, vf1;
        kf0.i = *(const int4*)(Klds + krow * 64 + (((0 + hi) ^ ((krow >> 1) & 3)) << 4));
        kf1.i = *(const int4*)(Klds + krow * 64 + (((2 + hi) ^ ((krow >> 1) & 3)) << 4));
        vf0.i = *(const int4*)(Vlds + col * 640 + (((kt * 4 + 0 + hi) ^ (col & 7)) << 4));
        vf1.i = *(const int4*)(Vlds + col * 640 + (((kt * 4 + 2 + hi) ^ (col & 7)) << 4));

        float mk[16];
        #pragma unroll
        for (int r = 0; r < 16; ++r) {
            const int patr = (r & 3) + 8 * (r >> 2);
            mk[r] = mlds[kbase + patr + 4 * hi];
        }

        #pragma unroll
        for (int jt = 0; jt < 2; ++jt) {
            const int jcol = jt0 + jt * 32 + col;
            f32x16 S;
            #pragma unroll
            for (int r = 0; r < 16; ++r) S[r] = 0.f;
            S = MFMA32(kf0.v, qf[jt][0].v, S);
            S = MFMA32(kf1.v, qf[jt][1].v, S);

            float sv[16];
            #pragma unroll
            for (int r = 0; r < 16; ++r) {
                const int patr = (r & 3) + 8 * (r >> 2);
                const int kk = kbase + patr + 4 * hi;
                float b = bpj[kk * N + jcol];
                sv[r] = fmaf(S[r] + b, mk[r], fmaf(100.f, mk[r], -100.f));
            }

            float mt = sv[0];
            #pragma unroll
            for (int r = 1; r < 16; ++r) mt = fmaxf(mt, sv[r]);
            mt = fmaxf(mt, __shfl_xor(mt, 32));

            if (__any(mt > mrun[jt] + 8.0f)) {
                float mnew = fmaxf(mrun[jt], mt);
                float rs = __expf(mrun[jt] - mnew);
                lsum[jt] *= rs;
                #pragma unroll
                for (int r = 0; r < 16; ++r) accO[jt][r] *= rs;
                mrun[jt] = mnew;
            }

            float pe[16];
            float ls = 0.f;
            #pragma unroll
            for (int r = 0; r < 16; ++r) {
                pe[r] = __expf(sv[r] - mrun[jt]);
                ls += pe[r];
            }
            lsum[jt] += ls;

            unsigned p[8];
            #pragma unroll
            for (int q = 0; q < 8; ++q) p[q] = pk_bf16(pe[2 * q], pe[2 * q + 1]);
            unsigned sp[8];
            #pragma unroll
            for (int q = 0; q < 8; ++q) sp[q] = (unsigned)__shfl_xor((int)p[q], 32);

            frag_u bf0, bf1;
            bf0.u[0] = hi ? sp[2] : p[0];
            bf0.u[1] = hi ? sp[3] : p[1];
            bf0.u[2] = hi ? p[2]  : sp[0];
            bf0.u[3] = hi ? p[3]  : sp[1];
            bf1.u[0] = hi ? sp[6] : p[4];
            bf1.u[1] = hi ? sp[7] : p[5];
            bf1.u[2] = hi ? p[6]  : sp[4];
            bf1.u[3] = hi ? p[7]  : sp[5];

            accO[jt] = MFMA32(vf0.v, bf0.v, accO[jt]);
            accO[jt] = MFMA32(vf1.v, bf1.v, accO[jt]);
        }
    }

    #pragma unroll
    for (int jt = 0; jt < 2; ++jt) {
        float lt = lsum[jt] + __shfl_xor(lsum[jt], 32);
        float inv = 1.0f / lt;
        const int jcol = jt0 + jt * 32 + col;
        #pragma unroll
        for (int r = 0; r < 16; ++r) {
            const int a = (r & 3) + 8 * (r >> 2) + 4 * hi;
            size_t off = (size_t)(h * 32 + a) * NPOS + (size_t)i * N + jcol;
            Ot[off] = accO[jt][r] * inv * Gt[off];
        }
    }
}

// ---------------- Kernel C: output projection ---------------- (unchanged)
__global__ __launch_bounds__(128)
void outproj_kernel(const float* __restrict__ Ot,
                    const float* __restrict__ Wo,
                    const float* __restrict__ bo,
                    const float* __restrict__ mask,
                    float* __restrict__ out) {
    __shared__ float osh[PC][C + 1];
    const int t = threadIdx.x;
    const int pos0 = blockIdx.x * PC;
    {
        int c = ((t & 31) << 2) | (t >> 5);
        const float4* src = (const float4*)(Ot + (size_t)t * NPOS + pos0);
        #pragma unroll
        for (int u = 0; u < 4; ++u) {
            float4 vv = src[u];
            osh[4*u+0][c] = vv.x; osh[4*u+1][c] = vv.y;
            osh[4*u+2][c] = vv.z; osh[4*u+3][c] = vv.w;
        }
    }
    __syncthreads();
    float acc[PC];
    float b = bo[t];
    #pragma unroll
    for (int p = 0; p < PC; p++) acc[p] = b;
    for (int c = 0; c < C; c++) {
        float wv = Wo[c * C + t];
        #pragma unroll
        for (int p = 0; p < PC; p++) acc[p] = fmaf(osh[p][c], wv, acc[p]);
    }
    #pragma unroll
    for (int p = 0; p < PC; p++)
        out[(size_t)(pos0 + p) * C + t] = acc[p] * mask[pos0 + p];
}

// ---------------- launch ----------------
extern "C" void kernel_launch(void* const* d_in, const int* in_sizes, int n_in,
                              void* d_out, int out_size, void* d_ws, size_t ws_size,
                              hipStream_t stream) {
    const float* x2d    = (const float*)d_in[0];
    const float* mask   = (const float*)d_in[1];
    const float* norm_w = (const float*)d_in[2];
    const float* norm_b = (const float*)d_in[3];
    const float* Wq     = (const float*)d_in[4];
    const float* Wk     = (const float*)d_in[5];
    const float* Wv     = (const float*)d_in[6];
    const float* Wb     = (const float*)d_in[7];
    const float* Wg     = (const float*)d_in[8];
    const float* bg     = (const float*)d_in[9];
    const float* Wo     = (const float*)d_in[10];
    const float* bo     = (const float*)d_in[11];
    float* out = (float*)d_out;

    float* Gt = (float*)d_ws;
    float* Bp = Gt + (size_t)NPOS * C;
    float* Ot = Bp + (size_t)H * NPOS;
    unsigned short* Qb  = (unsigned short*)(Ot + (size_t)NPOS * C);
    unsigned short* Kb  = Qb + (size_t)NPOS * C;
    unsigned short* Vta = Kb + (size_t)NPOS * C;
    unsigned short* WF  = Vta + (size_t)NPOS * C;   // 65536 bf16 = 128 KB

    wprep_kernel<<<32, 256, 0, stream>>>(Wq, Wk, Wv, Wg, WF);

    ln_proj_kernel<<<NPOS / 64, 256, 0, stream>>>(x2d, norm_w, norm_b, Wb, bg,
                                                  WF, Qb, Kb, Vta, Gt, Bp);

    attn_kernel<<<N * H, 320, 0, stream>>>(Qb, Kb, Vta, Gt, Bp, mask, Ot);

    outproj_kernel<<<NPOS / PC, 128, 0, stream>>>(Ot, Wo, bo, mask, out);
}

// Round 5
// 225.097 us; speedup vs baseline: 8.7883x; 1.3988x over previous
//
#include <hip/hip_runtime.h>
#include <hip/hip_bf16.h>
#include <math.h>

#define N 320
#define C 128
#define A 32
#define H 4
#define NPOS (N*N)

typedef __attribute__((ext_vector_type(8))) __bf16 bf16x8;
typedef __attribute__((ext_vector_type(16))) float f32x16;

union frag_u { int4 i; bf16x8 v; unsigned u[4]; };

#define MFMA32(va, vb, vc) __builtin_amdgcn_mfma_f32_32x32x16_bf16((va), (vb), (vc), 0, 0, 0)

// wave-local LDS fence: order ds_write -> ds_read within a wave without
// draining vmcnt (global stores stay in flight).
#define WAVE_LDS_FENCE() do { \
    asm volatile("s_waitcnt lgkmcnt(0)" ::: "memory"); \
    __builtin_amdgcn_sched_barrier(0); \
} while (0)

static __device__ __forceinline__ unsigned pk_bf16(float lo, float hi) {
    union { __hip_bfloat162 h; unsigned u; } cv;
    cv.h = __float22bfloat162_rn(make_float2(lo, hi));
    return cv.u;
}

static __device__ __forceinline__ float bf16_to_f32(unsigned short u) {
    union { unsigned u; float f; } c;
    c.u = ((unsigned)u) << 16;
    return c.f;
}

// ---------------- Kernel W: weights -> bf16 B-fragment order ----------------
// mats 0..3 = Wq(*isq), Wk, Wv, Wg (row = input channel c).
// mat 4 = Wo with rows permuted: frag row r' = h*32+a  <-  Wo row (r'&31)*4+(r'>>5).
__global__ __launch_bounds__(256)
void wprep_kernel(const float* __restrict__ Wq,
                  const float* __restrict__ Wk,
                  const float* __restrict__ Wv,
                  const float* __restrict__ Wg,
                  const float* __restrict__ Wo,
                  unsigned short* __restrict__ WF) {
    const float isq = 0.17677669529663687f; // 1/sqrt(32)
    int tid = blockIdx.x * 256 + threadIdx.x;   // 10240 total
    int lane = tid & 63;
    int kk = (tid >> 6) & 7;
    int ct = (tid >> 9) & 3;
    int mat = tid >> 11;                        // 0..4
    const float* src = (mat == 0) ? Wq : (mat == 1) ? Wk : (mat == 2) ? Wv
                     : (mat == 3) ? Wg : Wo;
    float scl = (mat == 0) ? isq : 1.0f;
    int col = ct * 32 + (lane & 31);
    int c0 = kk * 16 + (lane >> 5) * 8;
    float v[8];
    #pragma unroll
    for (int e = 0; e < 8; e++) {
        int rr = c0 + e;
        int srow = (mat == 4) ? (((rr & 31) << 2) | (rr >> 5)) : rr;
        v[e] = src[(size_t)srow * 128 + col] * scl;
    }
    int4 out;
    out.x = pk_bf16(v[0], v[1]);
    out.y = pk_bf16(v[2], v[3]);
    out.z = pk_bf16(v[4], v[5]);
    out.w = pk_bf16(v[6], v[7]);
    *(int4*)((char*)WF + (size_t)tid * 16) = out;
}

// ---------------- Kernel A: LayerNorm + MFMA projections ----------------
// 1600 blocks x 256 threads; 64 positions per block; wave w computes matrix w.
// Outputs: Qb/Kb bf16 rows [h][pos][a]; Vta bf16 planes [h*32+a][pos];
//          Gb bf16 planes [h*32+a][pos]; BpT f32 [h][j][k].
__global__ __launch_bounds__(256)
void ln_proj_kernel(const float* __restrict__ x2d,
                    const float* __restrict__ norm_w,
                    const float* __restrict__ norm_b,
                    const float* __restrict__ Wb,
                    const float* __restrict__ bg,
                    const unsigned short* __restrict__ WF,
                    unsigned short* __restrict__ Qb,
                    unsigned short* __restrict__ Kb,
                    unsigned short* __restrict__ Vta,
                    unsigned short* __restrict__ Gb,
                    float* __restrict__ BpT) {
    __shared__ __align__(16) unsigned char xnb[64 * 256];   // bf16 [64][128], swizzled granules
    __shared__ float stage[4][32 * 65];                     // per-wave f32 [ch][row] stage

    const int t = threadIdx.x;
    const int gpos0 = blockIdx.x * 64;

    // ---- Phase 1: LN + bias projection + bf16 pack to LDS ----
    {
        const int r = t >> 2, s = t & 3;
        const float4* src = (const float4*)(x2d + (size_t)(gpos0 + r) * 128 + s * 32);
        float4 xv[8];
        #pragma unroll
        for (int u = 0; u < 8; u++) xv[u] = src[u];
        float sum = 0.f, sq = 0.f;
        #pragma unroll
        for (int u = 0; u < 8; u++) {
            sum += xv[u].x + xv[u].y + xv[u].z + xv[u].w;
            sq += xv[u].x * xv[u].x + xv[u].y * xv[u].y
                + xv[u].z * xv[u].z + xv[u].w * xv[u].w;
        }
        sum += __shfl_xor(sum, 1); sum += __shfl_xor(sum, 2);
        sq  += __shfl_xor(sq, 1);  sq  += __shfl_xor(sq, 2);
        float mean = sum * (1.0f / 128.0f);
        float var  = sq * (1.0f / 128.0f) - mean * mean;
        float rstd = rsqrtf(var + 1e-5f);

        const float4* wsrc = (const float4*)(norm_w + s * 32);
        const float4* bsrc = (const float4*)(norm_b + s * 32);
        const float4* wb4  = (const float4*)Wb;
        float pb0 = 0.f, pb1 = 0.f, pb2 = 0.f, pb3 = 0.f;
        float4 xe;
        #pragma unroll
        for (int u = 0; u < 8; u++) {
            float4 wv = wsrc[u], bv = bsrc[u], x4 = xv[u];
            float4 xn;
            xn.x = (x4.x - mean) * rstd * wv.x + bv.x;
            xn.y = (x4.y - mean) * rstd * wv.y + bv.y;
            xn.z = (x4.z - mean) * rstd * wv.z + bv.z;
            xn.w = (x4.w - mean) * rstd * wv.w + bv.w;
            int cb = s * 32 + u * 4;
            float4 w0 = wb4[cb + 0], w1 = wb4[cb + 1], w2 = wb4[cb + 2], w3 = wb4[cb + 3];
            pb0 = fmaf(xn.x, w0.x, fmaf(xn.y, w1.x, fmaf(xn.z, w2.x, fmaf(xn.w, w3.x, pb0))));
            pb1 = fmaf(xn.x, w0.y, fmaf(xn.y, w1.y, fmaf(xn.z, w2.y, fmaf(xn.w, w3.y, pb1))));
            pb2 = fmaf(xn.x, w0.z, fmaf(xn.y, w1.z, fmaf(xn.z, w2.z, fmaf(xn.w, w3.z, pb2))));
            pb3 = fmaf(xn.x, w0.w, fmaf(xn.y, w1.w, fmaf(xn.z, w2.w, fmaf(xn.w, w3.w, pb3))));
            if (u & 1) {
                int g = s * 4 + (u >> 1);
                int4 gr;
                gr.x = pk_bf16(xe.x, xe.y);
                gr.y = pk_bf16(xe.z, xe.w);
                gr.z = pk_bf16(xn.x, xn.y);
                gr.w = pk_bf16(xn.z, xn.w);
                *(int4*)(xnb + r * 256 + ((g ^ (r & 7)) << 4)) = gr;
            } else {
                xe = xn;
            }
        }
        pb0 += __shfl_xor(pb0, 1); pb0 += __shfl_xor(pb0, 2);
        pb1 += __shfl_xor(pb1, 1); pb1 += __shfl_xor(pb1, 2);
        pb2 += __shfl_xor(pb2, 1); pb2 += __shfl_xor(pb2, 2);
        pb3 += __shfl_xor(pb3, 1); pb3 += __shfl_xor(pb3, 2);
        float pbsel = (s == 0) ? pb0 : (s == 1) ? pb1 : (s == 2) ? pb2 : pb3;
        // transposed bias: BpT[h][j][k], this position is (k=r1, j=r2)
        int r1 = gpos0 / N;
        int r2 = (gpos0 % N) + r;
        BpT[(size_t)s * NPOS + (size_t)r2 * N + r1] = pbsel;
    }
    __syncthreads();

    // ---- Phase 2+3: per-wave MFMA GEMM + epilogue ----
    const int lane = t & 63;
    const int w = t >> 6;
    const int col = lane & 31;
    const int hi = lane >> 5;

    frag_u af[2][8];
    #pragma unroll
    for (int rt = 0; rt < 2; rt++)
        #pragma unroll
        for (int kk = 0; kk < 8; kk++) {
            int row = rt * 32 + col;
            af[rt][kk].i = *(const int4*)(xnb + row * 256 + (((kk * 2 + hi) ^ (row & 7)) << 4));
        }

    const char* wf = (const char*)WF + (size_t)w * 4 * 8 * 1024;
    float* stage_w = stage[w];

    for (int ct = 0; ct < 4; ct++) {
        f32x16 acc0, acc1;
        #pragma unroll
        for (int r = 0; r < 16; r++) { acc0[r] = 0.f; acc1[r] = 0.f; }
        #pragma unroll
        for (int kk = 0; kk < 8; kk++) {
            frag_u bf;
            bf.i = *(const int4*)(wf + (ct * 8 + kk) * 1024 + lane * 16);
            acc0 = MFMA32(af[0][kk].v, bf.v, acc0);
            acc1 = MFMA32(af[1][kk].v, bf.v, acc1);
        }
        #pragma unroll
        for (int r = 0; r < 16; r++) {
            int patr = (r & 3) + 8 * (r >> 2) + 4 * hi;
            stage_w[col * 65 + patr] = acc0[r];
            stage_w[col * 65 + 32 + patr] = acc1[r];
        }
        WAVE_LDS_FENCE();   // lgkmcnt only: stage visible wave-wide, stores stay in flight
        if (w < 2) {
            // Q / K rows: Qb[h][pos][a] bf16
            char* dst = (w == 0) ? (char*)Qb : (char*)Kb;
            #pragma unroll
            for (int h = 0; h < 4; h++) {
                float f[8];
                #pragma unroll
                for (int u = 0; u < 8; u++) f[u] = stage_w[(u * 4 + h) * 65 + lane];
                int4 val;
                val.x = pk_bf16(f[0], f[1]);
                val.y = pk_bf16(f[2], f[3]);
                val.z = pk_bf16(f[4], f[5]);
                val.w = pk_bf16(f[6], f[7]);
                *(int4*)(dst + ((size_t)h * NPOS + gpos0 + lane) * 64 + ct * 16) = val;
            }
        } else if (w == 2) {
            // V planes: Vta[h*32+a][pos] bf16
            int cc = lane & 31, half = lane >> 5;
            int plane = (cc & 3) * 32 + ct * 8 + (cc >> 2);
            unsigned pk[16];
            #pragma unroll
            for (int j2 = 0; j2 < 16; j2++)
                pk[j2] = pk_bf16(stage_w[cc * 65 + half * 32 + 2 * j2],
                                 stage_w[cc * 65 + half * 32 + 2 * j2 + 1]);
            int4* dst = (int4*)((char*)Vta + ((size_t)plane * NPOS + gpos0 + half * 32) * 2);
            dst[0] = make_int4(pk[0], pk[1], pk[2], pk[3]);
            dst[1] = make_int4(pk[4], pk[5], pk[6], pk[7]);
            dst[2] = make_int4(pk[8], pk[9], pk[10], pk[11]);
            dst[3] = make_int4(pk[12], pk[13], pk[14], pk[15]);
        } else {
            // G planes: Gb[h*32+a][pos] bf16, sigmoid(acc + bg)
            int cc = lane & 31, half = lane >> 5;
            int plane = (cc & 3) * 32 + ct * 8 + (cc >> 2);
            float bgv = bg[ct * 32 + cc];
            unsigned pk[16];
            #pragma unroll
            for (int j2 = 0; j2 < 16; j2++) {
                float z0 = stage_w[cc * 65 + half * 32 + 2 * j2] + bgv;
                float z1 = stage_w[cc * 65 + half * 32 + 2 * j2 + 1] + bgv;
                float g0 = 1.0f / (1.0f + __expf(-z0));
                float g1 = 1.0f / (1.0f + __expf(-z1));
                pk[j2] = pk_bf16(g0, g1);
            }
            int4* dst = (int4*)((char*)Gb + ((size_t)plane * NPOS + gpos0 + half * 32) * 2);
            dst[0] = make_int4(pk[0], pk[1], pk[2], pk[3]);
            dst[1] = make_int4(pk[4], pk[5], pk[6], pk[7]);
            dst[2] = make_int4(pk[8], pk[9], pk[10], pk[11]);
            dst[3] = make_int4(pk[12], pk[13], pk[14], pk[15]);
        }
        WAVE_LDS_FENCE();   // reads done before next ct overwrites stage
    }
}

// ---------------- Kernel B: MFMA attention per (i,h) ----------------
// 5 waves x 64 j; swapped QK^T; float4 bias prefetch; bf16 Ob epilogue.
__global__ __launch_bounds__(320, 2)
void attn_kernel(const unsigned short* __restrict__ Qb,
                 const unsigned short* __restrict__ Kb,
                 const unsigned short* __restrict__ Vta,
                 const unsigned short* __restrict__ Gb,
                 const float* __restrict__ BpT,
                 const float* __restrict__ mask,
                 unsigned short* __restrict__ Ob) {
    __shared__ __align__(16) unsigned char smem[40960];   // K[20480] | V[20480]; reused as epilogue stage
    __shared__ float mlds[N];
    unsigned char* Klds = smem;
    unsigned char* Vlds = smem + 20480;

    const int i = blockIdx.x >> 2;
    const int h = blockIdx.x & 3;
    const int t = threadIdx.x;
    const int lane = t & 63;
    const int w = t >> 6;
    const int col = lane & 31;
    const int hi = lane >> 5;
    const int jt0 = w * 64;

    // Q fragments from global
    frag_u qf[2][2];
    const char* qbase = (const char*)Qb + ((size_t)h * NPOS + (size_t)i * N) * 64;
    #pragma unroll
    for (int jt = 0; jt < 2; ++jt) {
        int jrow = jt0 + jt * 32 + col;
        #pragma unroll
        for (int cf = 0; cf < 2; ++cf)
            qf[jt][cf].i = *(const int4*)(qbase + (size_t)jrow * 64 + cf * 32 + hi * 16);
    }

    // stage K rows (swizzled granule slots)
    const char* kbsrc = (const char*)Kb + ((size_t)h * NPOS + (size_t)i * N) * 64;
    #pragma unroll
    for (int it = 0; it < 4; ++it) {
        int tt = t + it * 320;
        int k = tt >> 2, gc = tt & 3;
        int4 val = *(const int4*)(kbsrc + (size_t)k * 64 + gc * 16);
        *(int4*)(Klds + k * 64 + ((gc ^ ((k >> 1) & 3)) << 4)) = val;
    }
    // stage V^T planes (swizzled)
    const char* vbsrc = (const char*)Vta + ((size_t)h * 32 * NPOS + (size_t)i * N) * 2;
    #pragma unroll
    for (int it = 0; it < 4; ++it) {
        int tt = t + it * 320;
        int a = tt / 40, kg = tt % 40;
        int4 val = *(const int4*)(vbsrc + (size_t)a * NPOS * 2 + kg * 16);
        *(int4*)(Vlds + a * 640 + ((kg ^ (a & 7)) << 4)) = val;
    }
    mlds[t] = mask[(size_t)i * N + t];
    __syncthreads();

    f32x16 accO[2];
    #pragma unroll
    for (int r = 0; r < 16; ++r) { accO[0][r] = 0.f; accO[1][r] = 0.f; }
    float mrun[2] = { -3e38f, -3e38f };
    float lsum[2] = { 0.f, 0.f };

    // bias row pointers (BpT[h][j][k]) with the lane's 4*hi k-offset folded in
    const float* br0 = BpT + (size_t)h * NPOS + (size_t)(jt0 + col) * N + 4 * hi;
    const float* br1 = br0 + (size_t)32 * N;

    float4 b0[4], b1[4];
    #pragma unroll
    for (int q = 0; q < 4; ++q) b0[q] = *(const float4*)(br0 + 8 * q);  // kt=0, jt=0

#define PROCESS_JT(JT, BB)                                                      \
    {                                                                           \
        const int jcol = jt0 + (JT) * 32 + col;                                 \
        f32x16 S;                                                               \
        _Pragma("unroll") for (int r = 0; r < 16; ++r) S[r] = 0.f;              \
        __builtin_amdgcn_s_setprio(1);                                          \
        S = MFMA32(kf0.v, qf[JT][0].v, S);                                      \
        S = MFMA32(kf1.v, qf[JT][1].v, S);                                      \
        __builtin_amdgcn_s_setprio(0);                                          \
        float bb[16];                                                           \
        _Pragma("unroll") for (int q = 0; q < 4; ++q) {                         \
            bb[4 * q + 0] = BB[q].x; bb[4 * q + 1] = BB[q].y;                   \
            bb[4 * q + 2] = BB[q].z; bb[4 * q + 3] = BB[q].w;                   \
        }                                                                       \
        float sv[16];                                                           \
        _Pragma("unroll") for (int r = 0; r < 16; ++r)                          \
            sv[r] = fmaf(S[r] + bb[r], mk[r], mk2[r]);                          \
        float mt = sv[0];                                                       \
        _Pragma("unroll") for (int r = 1; r < 16; ++r) mt = fmaxf(mt, sv[r]);   \
        mt = fmaxf(mt, __shfl_xor(mt, 32));                                     \
        if (__any(mt > mrun[JT] + 8.0f)) {                                      \
            float mnew = fmaxf(mrun[JT], mt);                                   \
            float rs = __expf(mrun[JT] - mnew);                                 \
            lsum[JT] *= rs;                                                     \
            _Pragma("unroll") for (int r = 0; r < 16; ++r) accO[JT][r] *= rs;   \
            mrun[JT] = mnew;                                                    \
        }                                                                       \
        float pe[16];                                                           \
        float ls = 0.f;                                                         \
        _Pragma("unroll") for (int r = 0; r < 16; ++r) {                        \
            pe[r] = __expf(sv[r] - mrun[JT]);                                   \
            ls += pe[r];                                                        \
        }                                                                       \
        lsum[JT] += ls;                                                         \
        unsigned p[8];                                                          \
        _Pragma("unroll") for (int q = 0; q < 8; ++q)                           \
            p[q] = pk_bf16(pe[2 * q], pe[2 * q + 1]);                           \
        unsigned sp[8];                                                         \
        _Pragma("unroll") for (int q = 0; q < 8; ++q)                           \
            sp[q] = (unsigned)__shfl_xor((int)p[q], 32);                        \
        frag_u bf0, bf1;                                                        \
        bf0.u[0] = hi ? sp[2] : p[0];                                           \
        bf0.u[1] = hi ? sp[3] : p[1];                                           \
        bf0.u[2] = hi ? p[2]  : sp[0];                                          \
        bf0.u[3] = hi ? p[3]  : sp[1];                                          \
        bf1.u[0] = hi ? sp[6] : p[4];                                           \
        bf1.u[1] = hi ? sp[7] : p[5];                                           \
        bf1.u[2] = hi ? p[6]  : sp[4];                                          \
        bf1.u[3] = hi ? p[7]  : sp[5];                                          \
        __builtin_amdgcn_s_setprio(1);                                          \
        accO[JT] = MFMA32(vf0.v, bf0.v, accO[JT]);                              \
        accO[JT] = MFMA32(vf1.v, bf1.v, accO[JT]);                              \
        __builtin_amdgcn_s_setprio(0);                                          \
    }

    for (int kt = 0; kt < 10; ++kt) {
        const int kbase = kt * 32;
        const int krow = kbase + col;
        frag_u kf0, kf1, vf0, vf1;
        kf0.i = *(const int4*)(Klds + krow * 64 + (((0 + hi) ^ ((krow >> 1) & 3)) << 4));
        kf1.i = *(const int4*)(Klds + krow * 64 + (((2 + hi) ^ ((krow >> 1) & 3)) << 4));
        vf0.i = *(const int4*)(Vlds + col * 640 + (((kt * 4 + 0 + hi) ^ (col & 7)) << 4));
        vf1.i = *(const int4*)(Vlds + col * 640 + (((kt * 4 + 2 + hi) ^ (col & 7)) << 4));

        // bias for jt=1 of this kt (latency hidden under jt=0 compute)
        #pragma unroll
        for (int q = 0; q < 4; ++q) b1[q] = *(const float4*)(br1 + kbase + 8 * q);

        float mk[16], mk2[16];
        #pragma unroll
        for (int r = 0; r < 16; ++r) {
            float m_ = mlds[kbase + (r & 3) + 8 * (r >> 2) + 4 * hi];
            mk[r] = m_;
            mk2[r] = fmaf(100.f, m_, -100.f);
        }

        PROCESS_JT(0, b0)

        // bias for jt=0 of next kt (latency hidden under jt=1 compute)
        if (kt < 9) {
            #pragma unroll
            for (int q = 0; q < 4; ++q) b0[q] = *(const float4*)(br0 + kbase + 32 + 8 * q);
        }

        PROCESS_JT(1, b1)
    }
#undef PROCESS_JT

    // ---- epilogue: normalize, gate, transpose via LDS, store bf16 rows ----
    __syncthreads();   // all waves done reading Klds/Vlds
    float* st = (float*)(smem + w * 8192);   // 32 rows x 33 f32 per jt
    const unsigned short* gbase = Gb + (size_t)h * 32 * NPOS + (size_t)i * N;

    #pragma unroll
    for (int jt = 0; jt < 2; ++jt) {
        float lt = lsum[jt] + __shfl_xor(lsum[jt], 32);
        float inv = 1.0f / lt;
        const int jcol = jt0 + jt * 32 + col;
        #pragma unroll
        for (int r = 0; r < 16; ++r) {
            const int a = (r & 3) + 8 * (r >> 2) + 4 * hi;
            float g = bf16_to_f32(gbase[(size_t)a * NPOS + jcol]);
            st[col * 33 + a] = accO[jt][r] * inv * g;
        }
        WAVE_LDS_FENCE();
        {
            int jj = lane & 31;
            int ah0 = hi * 16;
            unsigned pk8[8];
            #pragma unroll
            for (int e = 0; e < 8; ++e)
                pk8[e] = pk_bf16(st[jj * 33 + ah0 + 2 * e], st[jj * 33 + ah0 + 2 * e + 1]);
            char* dst = (char*)Ob + (((size_t)i * N + jt0 + jt * 32 + jj) * 128 + h * 32 + ah0) * 2;
            *(int4*)dst = make_int4(pk8[0], pk8[1], pk8[2], pk8[3]);
            *(int4*)(dst + 16) = make_int4(pk8[4], pk8[5], pk8[6], pk8[7]);
        }
        WAVE_LDS_FENCE();
    }
}

// ---------------- Kernel C: MFMA output projection ----------------
// 1600 blocks x 256 threads; 64 pos per block; wave w -> output cols [w*32, w*32+32).
__global__ __launch_bounds__(256)
void outproj_kernel(const unsigned short* __restrict__ Ob,
                    const unsigned short* __restrict__ WoF,
                    const float* __restrict__ bo,
                    const float* __restrict__ mask,
                    float* __restrict__ out) {
    __shared__ __align__(16) unsigned char obs[64 * 256];   // bf16 [64][128], swizzled
    __shared__ float stage[4][32 * 65];

    const int t = threadIdx.x;
    const int gpos0 = blockIdx.x * 64;

    // stage Ob tile (coalesced 64B per thread)
    {
        const int r = t >> 2, s = t & 3;
        const char* src = (const char*)Ob + ((size_t)(gpos0 + r) * 128 + s * 32) * 2;
        #pragma unroll
        for (int u = 0; u < 4; ++u) {
            int4 v = *(const int4*)(src + u * 16);
            int g = s * 4 + u;
            *(int4*)(obs + r * 256 + ((g ^ (r & 7)) << 4)) = v;
        }
    }
    __syncthreads();

    const int lane = t & 63;
    const int w = t >> 6;
    const int col = lane & 31;
    const int hi = lane >> 5;

    f32x16 acc0, acc1;
    float bocol = bo[w * 32 + col];
    #pragma unroll
    for (int r = 0; r < 16; ++r) { acc0[r] = bocol; acc1[r] = bocol; }

    const char* wf = (const char*)WoF + (size_t)w * 8 * 1024;
    #pragma unroll
    for (int kk = 0; kk < 8; ++kk) {
        frag_u bf, a0, a1;
        bf.i = *(const int4*)(wf + kk * 1024 + lane * 16);
        int row0 = col, row1 = 32 + col;
        a0.i = *(const int4*)(obs + row0 * 256 + (((kk * 2 + hi) ^ (row0 & 7)) << 4));
        a1.i = *(const int4*)(obs + row1 * 256 + (((kk * 2 + hi) ^ (row1 & 7)) << 4));
        acc0 = MFMA32(a0.v, bf.v, acc0);
        acc1 = MFMA32(a1.v, bf.v, acc1);
    }

    float* st = stage[w];
    #pragma unroll
    for (int r = 0; r < 16; ++r) {
        int patr = (r & 3) + 8 * (r >> 2) + 4 * hi;
        st[col * 65 + patr] = acc0[r];
        st[col * 65 + 32 + patr] = acc1[r];
    }
    WAVE_LDS_FENCE();
    {
        int row = lane;   // 0..63
        float mv = mask[gpos0 + row];
        float4* dst = (float4*)(out + (size_t)(gpos0 + row) * 128 + w * 32);
        #pragma unroll
        for (int u = 0; u < 8; ++u) {
            float4 o;
            o.x = st[(4 * u + 0) * 65 + row] * mv;
            o.y = st[(4 * u + 1) * 65 + row] * mv;
            o.z = st[(4 * u + 2) * 65 + row] * mv;
            o.w = st[(4 * u + 3) * 65 + row] * mv;
            dst[u] = o;
        }
    }
}

// ---------------- launch ----------------
extern "C" void kernel_launch(void* const* d_in, const int* in_sizes, int n_in,
                              void* d_out, int out_size, void* d_ws, size_t ws_size,
                              hipStream_t stream) {
    const float* x2d    = (const float*)d_in[0];
    const float* mask   = (const float*)d_in[1];
    const float* norm_w = (const float*)d_in[2];
    const float* norm_b = (const float*)d_in[3];
    const float* Wq     = (const float*)d_in[4];
    const float* Wk     = (const float*)d_in[5];
    const float* Wv     = (const float*)d_in[6];
    const float* Wb     = (const float*)d_in[7];
    const float* Wg     = (const float*)d_in[8];
    const float* bg     = (const float*)d_in[9];
    const float* Wo     = (const float*)d_in[10];
    const float* bo     = (const float*)d_in[11];
    float* out = (float*)d_out;

    // workspace carve (bytes): BpT f32[H*NPOS]; bf16: Qb,Kb,Vta,Gb,Ob [NPOS*C]; WF bf16[5*16384]
    char* ws = (char*)d_ws;
    float* BpT = (float*)ws;                                   ws += (size_t)H * NPOS * 4;
    unsigned short* Qb  = (unsigned short*)ws;                 ws += (size_t)NPOS * C * 2;
    unsigned short* Kb  = (unsigned short*)ws;                 ws += (size_t)NPOS * C * 2;
    unsigned short* Vta = (unsigned short*)ws;                 ws += (size_t)NPOS * C * 2;
    unsigned short* Gb  = (unsigned short*)ws;                 ws += (size_t)NPOS * C * 2;
    unsigned short* Ob  = (unsigned short*)ws;                 ws += (size_t)NPOS * C * 2;
    unsigned short* WF  = (unsigned short*)ws;                 // 5 * 32768 B
    unsigned short* WoF = WF + (size_t)4 * 16384;

    wprep_kernel<<<40, 256, 0, stream>>>(Wq, Wk, Wv, Wg, Wo, WF);

    ln_proj_kernel<<<NPOS / 64, 256, 0, stream>>>(x2d, norm_w, norm_b, Wb, bg,
                                                  WF, Qb, Kb, Vta, Gb, BpT);

    attn_kernel<<<N * H, 320, 0, stream>>>(Qb, Kb, Vta, Gb, BpT, mask, Ob);

    outproj_kernel<<<NPOS / 64, 256, 0, stream>>>(Ob, WoF, bo, mask, out);
}